// Round 9
// baseline (114.793 us; speedup 1.0000x reference)
//
#include <hip/hip_runtime.h>
#include <hip/hip_bf16.h>
#include <stdint.h>

// Problem constants
#define BDIM 4096
#define CDIM 10000
#define DDIM 512
#define CPAD 10112       // 79 * 128, padded N so GEMM loads need no guards
#define NTILES 2528      // 32 * 79 output tiles
#define GRID 512         // 2 blocks/CU, persistent-ish
#define STRIDE_TILE (2 * 128 * DDIM)  // B elem advance per step (bn += 2)

typedef __bf16 bf16_t;
typedef __attribute__((ext_vector_type(2))) __bf16 bf16x2;
typedef __attribute__((ext_vector_type(8))) __bf16 bf16x8;
typedef __attribute__((ext_vector_type(2))) float f32x2;
typedef __attribute__((ext_vector_type(4))) float f32x4;

__device__ __forceinline__ void gl_lds16(const void* g, void* s) {
  __builtin_amdgcn_global_load_lds(
      (const __attribute__((address_space(1))) void*)g,
      (__attribute__((address_space(3))) void*)s, 16, 0, 0);
}

// --- fused prep: rows [0,BDIM) = feat, rows [BDIM,BDIM+CPAD) = weights ---
__global__ __launch_bounds__(256) void prep(
    const float* __restrict__ feat, const float* __restrict__ w,
    bf16_t* __restrict__ fb, bf16_t* __restrict__ wb,
    float* __restrict__ f2, float* __restrict__ w2,
    float* __restrict__ wout) {
  const int b = blockIdx.x;
  const int t = threadIdx.x;
  __shared__ float red[4];
  if (b < BDIM) {
    const f32x2 v = ((const f32x2*)(feat + (size_t)b * DDIM))[t];
    bf16x2 o;
    o.x = (__bf16)v.x;
    o.y = (__bf16)v.y;
    ((bf16x2*)fb)[(size_t)b * (DDIM / 2) + t] = o;
    float ss = v.x * v.x + v.y * v.y;
#pragma unroll
    for (int off = 32; off > 0; off >>= 1) ss += __shfl_down(ss, off);
    if ((t & 63) == 0) red[t >> 6] = ss;
    __syncthreads();
    if (t == 0) f2[b] = red[0] + red[1] + red[2] + red[3];
  } else {
    const int row = b - BDIM;
    if (row < CDIM) {
      const f32x2 v = ((const f32x2*)(w + (size_t)row * DDIM))[t];
      __builtin_nontemporal_store(v, (f32x2*)(wout + (size_t)row * DDIM) + t);
      bf16x2 o;
      o.x = (__bf16)v.x;
      o.y = (__bf16)v.y;
      ((bf16x2*)wb)[(size_t)row * (DDIM / 2) + t] = o;
      float ss = v.x * v.x + v.y * v.y;
#pragma unroll
      for (int off = 32; off > 0; off >>= 1) ss += __shfl_down(ss, off);
      if ((t & 63) == 0) red[t >> 6] = ss;
      __syncthreads();
      if (t == 0) w2[row] = red[0] + red[1] + red[2] + red[3];
    } else {
      bf16x2 z;
      z.x = (__bf16)0.0f;
      z.y = (__bf16)0.0f;
      ((bf16x2*)wb)[(size_t)row * (DDIM / 2) + t] = z;
      if (t == 0) w2[row] = 0.0f;
    }
  }
}

// --- persistent GEMM + cross-tile store-pipelined RBF epilogue ---
// Each block: bm fixed, walks 4-5 bn tiles. Tile j's exp results stash in
// 64 VGPRs; during tile j+1's K-loop, one 8x128 slice per K-iter is
// reshuffled through LDS sbuf and NT-stored (2 stores/iter/thread).
// Barriers: raw s_barrier with counted vmcnt(4) -> drain stores never
// block, frag-tile loads guaranteed landed. 3-buffer staging (R4 proven).
__global__ __launch_bounds__(256, 2) void rbf_gemm(
    const bf16_t* __restrict__ A,   // [4096][512] bf16  (feat)
    const bf16_t* __restrict__ Bw,  // [10112][512] bf16 (weights, padded)
    const float* __restrict__ f2g, const float* __restrict__ w2g,
    float* __restrict__ out) {
  __shared__ __align__(16) bf16_t stg[3 * 8192];   // 48 KB: 3 x (A 8KB|B 8KB)
  __shared__ __align__(16) float sbuf[2][8][132];  // 8448 B slice reshuffle
  __shared__ float w2all[5][128];                  // per-tile w2 rows

  const int b = blockIdx.x;
  const int t = threadIdx.x;
  const int lane = t & 63;
  const int wv = t >> 6;
  const int wm = (wv >> 1) * 64;  // feat-row group of this wave
  const int wn = (wv & 1) * 64;   // weight-col group of this wave
  const int fr = lane & 15;
  const int k8 = (lane >> 4) * 8;
  const int c_l = (lane >> 4) * 4;

  // tile decode: virtual bid v = b + 512*s keeps XCD chunk + bm fixed,
  // bn advances by 2 per step (same bijective swizzle as R5).
  const int wg0 = (b & 7) * 316 + (b >> 3);
  const int bm = wg0 & 31;
  const int bn0 = wg0 >> 5;
  const int s_total = (NTILES - 1 - b) / GRID + 1;  // 4 or 5

  // prologue: per-thread f2 fragment rows + all tiles' w2 rows
  float f2r[4];
#pragma unroll
  for (int mi = 0; mi < 4; ++mi)
    f2r[mi] = f2g[bm * 128 + wm + mi * 16 + fr];
  for (int s_ = 0; s_ < s_total; ++s_)
    if (t < 128) w2all[s_][t] = w2g[(bn0 + 2 * s_) * 128 + t];

  // staging addressing: 4 threads x 16B per 32-elem row; 64 rows per call
  const int sr = t >> 2;
  const int sc = (t & 3) * 8;
  const bf16_t* ga0 = A + (size_t)(bm * 128 + sr) * DDIM + sc;
  const bf16_t* ga1 = ga0 + (size_t)64 * DDIM;
  const bf16_t* gb_cur = Bw + (size_t)(bn0 * 128 + sr) * DDIM + sc;
  const bf16_t* gb_nxt = gb_cur + (s_total > 1 ? STRIDE_TILE : 0);

#define STAGE(off, ak, bptr, bk)                       \
  do {                                                 \
    gl_lds16(ga0 + (ak), stg + (off) + t * 8);         \
    gl_lds16(ga1 + (ak), stg + (off) + 2048 + t * 8);  \
    gl_lds16((bptr) + (bk), stg + (off) + 4096 + t * 8);          \
    gl_lds16((bptr) + (bk) + (size_t)64 * DDIM,                   \
             stg + (off) + 4096 + 2048 + t * 8);                  \
  } while (0)

  // slice k of the PREVIOUS tile's stash -> sbuf[k&1]
#define SLICEW(k)                                                        \
  do {                                                                   \
    if (((wv >> 1) == ((k) >> 3)) && ((fr >> 3) == ((k) & 1))) {         \
      const int row_ = fr & 7;                                           \
      _Pragma("unroll") for (int ni = 0; ni < 4; ++ni)                   \
          *(f32x4*)&sbuf[(k) & 1][row_][wn + ni * 16 + c_l] =            \
              stash[((k) >> 1) & 3][ni];                                 \
    }                                                                    \
  } while (0)

  // coalesced NT drain of sbuf[k&1] -> both output segments
#define DRAIN(k, bnd)                                                    \
  do {                                                                   \
    const int r_ = t >> 5;                                               \
    const int c_ = (t & 31) * 4;                                         \
    const f32x4 v_ = *(const f32x4*)&sbuf[(k) & 1][r_][c_];              \
    const int gcol_ = (bnd) * 128 + c_;                                  \
    if (gcol_ < CDIM) {                                                  \
      float* orow_ =                                                     \
          out + (size_t)(bm * 128 + (k) * 8 + r_) * CDIM + gcol_;        \
      __builtin_nontemporal_store(v_, (f32x4*)orow_);                    \
      __builtin_nontemporal_store(v_, (f32x4*)(orow_ + BC));             \
    }                                                                    \
  } while (0)

  const size_t BC = (size_t)BDIM * CDIM;

  f32x4 acc[4][4];
  f32x4 stash[4][4];
#pragma unroll
  for (int i = 0; i < 4; ++i)
#pragma unroll
    for (int j = 0; j < 4; ++j) acc[i][j] = (f32x4){0.f, 0.f, 0.f, 0.f};

  // prologue: stage k0,k1 of tile 0; full drain (also covers w2all/f2r)
  STAGE(0, 0, gb_cur, 0);
  STAGE(8192, 32, gb_cur, 32);
  __syncthreads();

  int o0 = 0, o1 = 8192, o2 = 16384;
  int bn_dr = bn0;  // bn of the tile being drained (tile s-1)

  for (int s = 0; s < s_total; ++s) {
    const bool hasst = (s > 0);
#pragma unroll
    for (int kt = 0; kt < 16; ++kt) {
      // (1) drain slice kt-1 of previous tile (2 NT stores)
      if (hasst && kt >= 1) DRAIN(kt - 1, bn_dr);
      asm volatile("" ::: "memory");
      // (2) stage k-tile kt+2 (4 gl_lds); last tile: dummy re-stage
      if (kt <= 13)
        STAGE(o2, ((kt + 2) & 15) * 32, gb_cur, (kt + 2) * 32);
      else
        STAGE(o2, ((kt + 2) & 15) * 32, gb_nxt, ((kt + 2) & 15) * 32);
      asm volatile("" ::: "memory");
      // (3) reshuffle slice kt of previous tile's stash into sbuf
      if (hasst) SLICEW(kt);
      // (4) frags + MFMA from buffer o0
      {
        const bf16_t* Ab = stg + o0;
        bf16x8 af[4], wf[4];
#pragma unroll
        for (int mi = 0; mi < 4; ++mi)
          af[mi] = *(const bf16x8*)(Ab + (wm + mi * 16 + fr) * 32 + k8);
#pragma unroll
        for (int ni = 0; ni < 4; ++ni)
          wf[ni] = *(const bf16x8*)(Ab + 4096 + (wn + ni * 16 + fr) * 32 + k8);
        __builtin_amdgcn_s_setprio(1);
#pragma unroll
        for (int mi = 0; mi < 4; ++mi)
#pragma unroll
          for (int ni = 0; ni < 4; ++ni)
            acc[mi][ni] = __builtin_amdgcn_mfma_f32_16x16x32_bf16(
                wf[ni], af[mi], acc[mi][ni], 0, 0, 0);  // swapped: D = W F^T
        __builtin_amdgcn_s_setprio(0);
      }
      // (5) counted barrier: frag loads for next iter landed; stores fly
      asm volatile("s_waitcnt vmcnt(4) lgkmcnt(0)" ::: "memory");
      __builtin_amdgcn_s_barrier();
      const int tmp = o0;
      o0 = o1;
      o1 = o2;
      o2 = tmp;
    }
    // post-K: final slice of previous tile, then exp -> stash, reset acc
    if (hasst) DRAIN(15, bn_dr);
#pragma unroll
    for (int mi = 0; mi < 4; ++mi) {
      const float fv = f2r[mi];
#pragma unroll
      for (int ni = 0; ni < 4; ++ni) {
        const f32x4 w4 = *(const f32x4*)&w2all[s][wn + ni * 16 + c_l];
        f32x4 st;
#pragma unroll
        for (int j = 0; j < 4; ++j) {
          float m = fv + w4[j] - 2.0f * acc[mi][ni][j];
          m = fmaxf(m, 0.0f);
          st[j] = __expf(-0.01f * m);
        }
        stash[mi][ni] = st;
        acc[mi][ni] = (f32x4){0.f, 0.f, 0.f, 0.f};
      }
    }
    bn_dr = bn0 + 2 * s;  // drained during next tile (or tail)
    gb_cur = gb_nxt;
    if (s + 2 < s_total) gb_nxt += STRIDE_TILE;
  }

  // tail: drain the last tile's stash, 16 lgkm-barrier mini-phases
#pragma unroll
  for (int k = 0; k < 16; ++k) {
    SLICEW(k);
    asm volatile("s_waitcnt lgkmcnt(0)" ::: "memory");
    __builtin_amdgcn_s_barrier();
    DRAIN(k, bn_dr);
  }
#undef STAGE
#undef SLICEW
#undef DRAIN
}

extern "C" void kernel_launch(void* const* d_in, const int* in_sizes, int n_in,
                              void* d_out, int out_size, void* d_ws,
                              size_t ws_size, hipStream_t stream) {
  const float* feat = (const float*)d_in[0];
  // d_in[1] = label (int64) — unused by the reference math
  const float* w = (const float*)d_in[2];
  float* out = (float*)d_out;

  char* ws = (char*)d_ws;
  bf16_t* fb = (bf16_t*)ws;                        // 4096*512*2  = 4,194,304 B
  bf16_t* wb = (bf16_t*)(ws + 4194304);            // 10112*512*2 = 10,354,688 B
  float* f2 = (float*)(ws + 4194304 + 10354688);   // 16,384 B
  float* w2 = (float*)(ws + 4194304 + 10354688 + 16384);  // 40,448 B

  float* wout = out + (size_t)2 * BDIM * CDIM;  // weights passthrough segment

  prep<<<BDIM + CPAD, 256, 0, stream>>>(feat, w, fb, wb, f2, w2, wout);
  rbf_gemm<<<GRID, 256, 0, stream>>>(fb, wb, f2, w2, out);
}